// Round 1
// baseline (616.243 us; speedup 1.0000x reference)
//
#include <hip/hip_runtime.h>
#include <stdint.h>

// MoE block: B=2, L=2048 (T=4096 tokens), E=1024, H=2048, N=8 experts, top-2.
// Key insight: reference's dense all-expert FFN is multiplied by weights that are
// exactly zero outside top-2 -> compute only top-2 experts (103 GFLOP vs 412).
// bf16 MFMA path (no fp32 MFMA on CDNA4); threshold 5.1e-2 tolerates bf16.

#define T_TOKENS 4096
#define E_DIM 1024
#define H_DIM 2048
#define BM 128
#define BN 128
#define BK 32
#define MAX_TILES 72  // sum_e ceil(cnt_e/128) <= 8192/128 + 8

typedef __attribute__((ext_vector_type(8))) short bf16x8;
typedef __attribute__((ext_vector_type(8))) unsigned short u16x8;
typedef __attribute__((ext_vector_type(4))) float f32x4;

__device__ __forceinline__ unsigned short f2bf(float f) {
  unsigned u = __float_as_uint(f);
  u += 0x7fff + ((u >> 16) & 1);  // RNE
  return (unsigned short)(u >> 16);
}

__device__ __forceinline__ void gll16(const void* g, void* l) {
  // global -> LDS async, 16B per lane. LDS dest is wave-uniform base + lane*16.
  __builtin_amdgcn_global_load_lds(
      (__attribute__((address_space(1))) void*)(uintptr_t)g,
      (__attribute__((address_space(3))) void*)l, 16, 0, 0);
}

// ---------------- router: logits = x . gate, top2 + softmax -----------------
__global__ __launch_bounds__(256) void router_kernel(
    const float* __restrict__ x, const float* __restrict__ gate,
    int* __restrict__ cnt, int2* __restrict__ tok_e,
    int2* __restrict__ tok_pos, float2* __restrict__ tok_w) {
  int lane = threadIdx.x & 63;
  int wv = threadIdx.x >> 6;
  int t = blockIdx.x * 4 + wv;
  const float* xr = x + (size_t)t * E_DIM;
  float acc[8];
#pragma unroll
  for (int n = 0; n < 8; n++) acc[n] = 0.f;
#pragma unroll
  for (int i = 0; i < 16; i++) {
    int k = i * 64 + lane;
    float xv = xr[k];
    const float4* gp = (const float4*)(gate + (size_t)k * 8);
    float4 g0 = gp[0], g1 = gp[1];
    acc[0] += xv * g0.x; acc[1] += xv * g0.y;
    acc[2] += xv * g0.z; acc[3] += xv * g0.w;
    acc[4] += xv * g1.x; acc[5] += xv * g1.y;
    acc[6] += xv * g1.z; acc[7] += xv * g1.w;
  }
#pragma unroll
  for (int s = 32; s >= 1; s >>= 1) {
#pragma unroll
    for (int n = 0; n < 8; n++) acc[n] += __shfl_xor(acc[n], s, 64);
  }
  if (lane == 0) {
    int i0 = 0; float v0 = acc[0];
#pragma unroll
    for (int n = 1; n < 8; n++) if (acc[n] > v0) { v0 = acc[n]; i0 = n; }
    int i1 = -1; float v1 = -3.4e38f;
#pragma unroll
    for (int n = 0; n < 8; n++) if (n != i0 && acc[n] > v1) { v1 = acc[n]; i1 = n; }
    float e1 = __expf(v1 - v0);
    float inv = 1.f / (1.f + e1);
    int p0 = atomicAdd(&cnt[i0], 1);
    int p1 = atomicAdd(&cnt[i1], 1);
    tok_e[t] = make_int2(i0, i1);
    tok_pos[t] = make_int2(p0, p1);
    tok_w[t] = make_float2(inv, e1 * inv);
  }
}

__global__ __launch_bounds__(256) void scatter_kernel(
    const int* __restrict__ cnt, const int2* __restrict__ tok_e,
    const int2* __restrict__ tok_pos, int* __restrict__ tlist,
    int2* __restrict__ tok_slot) {
  int t = blockIdx.x * 256 + threadIdx.x;
  if (t >= T_TOKENS) return;
  int offs[8]; int a = 0;
#pragma unroll
  for (int e = 0; e < 8; e++) { offs[e] = a; a += cnt[e]; }
  int2 te = tok_e[t]; int2 tp = tok_pos[t];
  int s0 = offs[te.x] + tp.x, s1 = offs[te.y] + tp.y;
  tlist[s0] = t; tlist[s1] = t;
  tok_slot[t] = make_int2(s0, s1);
}

// ---------------- fp32 -> bf16 conversions -----------------
__global__ __launch_bounds__(256) void convert_x_kernel(
    const float* __restrict__ x, unsigned short* __restrict__ xb) {
  size_t i = ((size_t)blockIdx.x * 256 + threadIdx.x) * 8;
  float4 a = *(const float4*)(x + i);
  float4 b = *(const float4*)(x + i + 4);
  u16x8 o;
  o[0] = f2bf(a.x); o[1] = f2bf(a.y); o[2] = f2bf(a.z); o[3] = f2bf(a.w);
  o[4] = f2bf(b.x); o[5] = f2bf(b.y); o[6] = f2bf(b.z); o[7] = f2bf(b.w);
  *(u16x8*)(xb + i) = o;
}

// src fp32 [R][C] per batch z -> dst bf16 [C][R] (K-contiguous for MFMA B frags)
__global__ __launch_bounds__(256) void transpose_convert_kernel(
    const float* __restrict__ src, unsigned short* __restrict__ dst, int R, int C) {
  __shared__ float tile[64][65];
  size_t bofs = (size_t)blockIdx.z * R * C;
  const float* s = src + bofs;
  unsigned short* d = dst + bofs;
  int r0 = blockIdx.y * 64, c0 = blockIdx.x * 64;
  int tr = threadIdx.x >> 2;
  int tc = (threadIdx.x & 3) * 16;
  const float* sp = s + (size_t)(r0 + tr) * C + c0 + tc;
#pragma unroll
  for (int j = 0; j < 4; j++) {
    float4 v = ((const float4*)sp)[j];
    tile[tr][tc + j * 4 + 0] = v.x; tile[tr][tc + j * 4 + 1] = v.y;
    tile[tr][tc + j * 4 + 2] = v.z; tile[tr][tc + j * 4 + 3] = v.w;
  }
  __syncthreads();
  int co = tr;   // dst row (original col)
  int rc = tc;   // chunk of 16 original rows
  u16x8 o0, o1;
#pragma unroll
  for (int j = 0; j < 8; j++) o0[j] = f2bf(tile[rc + j][co]);
#pragma unroll
  for (int j = 0; j < 8; j++) o1[j] = f2bf(tile[rc + 8 + j][co]);
  unsigned short* dp = d + (size_t)(c0 + co) * R + r0 + rc;
  *(u16x8*)dp = o0;
  *(u16x8*)(dp + 8) = o1;
}

// ---------------- tile mapping helper (per-expert row tiles) ----------------
__device__ __forceinline__ bool map_tile(const int* cnt, int tile, int& eSel,
                                         int& slot0, int& rows) {
  eSel = -1;
  int acc = 0, off = 0;
  for (int e = 0; e < 8; e++) {
    int ce = cnt[e];
    int te = (ce + BM - 1) / BM;
    if (eSel < 0 && tile < acc + te) {
      eSel = e;
      int tin = tile - acc;
      slot0 = off + tin * BM;
      rows = min(BM, ce - tin * BM);
    }
    acc += te; off += ce;
  }
  return eSel >= 0;
}

// ------- GEMM1: gathered X[slot] @ {w0t,w1t}  -> M = silu(h0)*h1 (bf16) -------
__global__ __launch_bounds__(256) void gemm1_kernel(
    const unsigned short* __restrict__ xb,    // [4096][1024] bf16
    const unsigned short* __restrict__ w0t,   // [8][2048][1024] bf16 (h-major)
    const unsigned short* __restrict__ w1t,
    const int* __restrict__ cnt, const int* __restrict__ tlist,
    unsigned short* __restrict__ Mbuf) {      // [8192][2048] bf16
  __shared__ alignas(16) unsigned short As[BM * BK];
  __shared__ alignas(16) unsigned short B0s[BN * BK];
  __shared__ alignas(16) unsigned short B1s[BN * BK];

  int eSel, slot0, rows;
  if (!map_tile(cnt, blockIdx.y, eSel, slot0, rows)) return;
  int h0 = blockIdx.x * BN;

  int tid = threadIdx.x, lane = tid & 63, wv = tid >> 6;
  // staging geometry: wave wv covers rows [wv*32, wv*32+32), 2 gll instrs each
  int rr0 = wv * 32 + (lane >> 2);
  int rr1 = rr0 + 16;
  int colE = (lane & 3) * 8;
  int ra0 = min(rr0, rows - 1), ra1 = min(rr1, rows - 1);
  const unsigned short* aS0 = xb + (size_t)tlist[slot0 + ra0] * E_DIM + colE;
  const unsigned short* aS1 = xb + (size_t)tlist[slot0 + ra1] * E_DIM + colE;
  const unsigned short* b0S0 = w0t + ((size_t)eSel * H_DIM + h0 + rr0) * E_DIM + colE;
  const unsigned short* b0S1 = w0t + ((size_t)eSel * H_DIM + h0 + rr1) * E_DIM + colE;
  const unsigned short* b1S0 = w1t + ((size_t)eSel * H_DIM + h0 + rr0) * E_DIM + colE;
  const unsigned short* b1S1 = w1t + ((size_t)eSel * H_DIM + h0 + rr1) * E_DIM + colE;

  f32x4 acc0[4][4], acc1[4][4];
  f32x4 fz = {0.f, 0.f, 0.f, 0.f};
#pragma unroll
  for (int m = 0; m < 4; m++)
#pragma unroll
    for (int n = 0; n < 4; n++) { acc0[m][n] = fz; acc1[m][n] = fz; }

  unsigned short* As_w = &As[wv * 1024];
  unsigned short* B0s_w = &B0s[wv * 1024];
  unsigned short* B1s_w = &B1s[wv * 1024];
  int rbase = (wv >> 1) * 64, cbase = (wv & 1) * 64;
  int fr = lane & 15, fk = (lane >> 4) * 8;

  for (int k0 = 0; k0 < E_DIM; k0 += BK) {
    gll16(aS0 + k0, As_w);
    gll16(aS1 + k0, As_w + 512);
    gll16(b0S0 + k0, B0s_w);
    gll16(b0S1 + k0, B0s_w + 512);
    gll16(b1S0 + k0, B1s_w);
    gll16(b1S1 + k0, B1s_w + 512);
    __syncthreads();
    bf16x8 a[4], b0[4], b1[4];
#pragma unroll
    for (int m = 0; m < 4; m++)
      a[m] = *(const bf16x8*)&As[(rbase + m * 16 + fr) * BK + fk];
#pragma unroll
    for (int n = 0; n < 4; n++) {
      b0[n] = *(const bf16x8*)&B0s[(cbase + n * 16 + fr) * BK + fk];
      b1[n] = *(const bf16x8*)&B1s[(cbase + n * 16 + fr) * BK + fk];
    }
#pragma unroll
    for (int m = 0; m < 4; m++)
#pragma unroll
      for (int n = 0; n < 4; n++) {
        acc0[m][n] = __builtin_amdgcn_mfma_f32_16x16x32_bf16(a[m], b0[n], acc0[m][n], 0, 0, 0);
        acc1[m][n] = __builtin_amdgcn_mfma_f32_16x16x32_bf16(a[m], b1[n], acc1[m][n], 0, 0, 0);
      }
    __syncthreads();
  }
  int rj = (lane >> 4) * 4;
#pragma unroll
  for (int m = 0; m < 4; m++) {
#pragma unroll
    for (int j = 0; j < 4; j++) {
      int r = rbase + m * 16 + rj + j;
      if (r < rows) {
        size_t rowp = (size_t)(slot0 + r) * H_DIM + h0 + cbase + fr;
#pragma unroll
        for (int n = 0; n < 4; n++) {
          float v0 = acc0[m][n][j], v1 = acc1[m][n][j];
          float mv = v0 / (1.f + __expf(-v0)) * v1;  // silu(h0)*h1
          Mbuf[rowp + n * 16] = f2bf(mv);
        }
      }
    }
  }
}

// ------- GEMM2: M[slot] @ wot -> O (fp32) -------
__global__ __launch_bounds__(256) void gemm2_kernel(
    const unsigned short* __restrict__ Mbuf,  // [8192][2048] bf16
    const unsigned short* __restrict__ wot,   // [8][1024][2048] bf16 (eo-major)
    const int* __restrict__ cnt,
    float* __restrict__ Obuf) {               // [8192][1024] fp32
  __shared__ alignas(16) unsigned short As[BM * BK];
  __shared__ alignas(16) unsigned short Bs[BN * BK];

  int eSel, slot0, rows;
  if (!map_tile(cnt, blockIdx.y, eSel, slot0, rows)) return;
  int eo0 = blockIdx.x * BN;

  int tid = threadIdx.x, lane = tid & 63, wv = tid >> 6;
  int rr0 = wv * 32 + (lane >> 2);
  int rr1 = rr0 + 16;
  int colE = (lane & 3) * 8;
  int ra0 = min(rr0, rows - 1), ra1 = min(rr1, rows - 1);
  const unsigned short* aS0 = Mbuf + (size_t)(slot0 + ra0) * H_DIM + colE;
  const unsigned short* aS1 = Mbuf + (size_t)(slot0 + ra1) * H_DIM + colE;
  const unsigned short* bS0 = wot + ((size_t)eSel * E_DIM + eo0 + rr0) * H_DIM + colE;
  const unsigned short* bS1 = wot + ((size_t)eSel * E_DIM + eo0 + rr1) * H_DIM + colE;

  f32x4 acc[4][4];
  f32x4 fz = {0.f, 0.f, 0.f, 0.f};
#pragma unroll
  for (int m = 0; m < 4; m++)
#pragma unroll
    for (int n = 0; n < 4; n++) acc[m][n] = fz;

  unsigned short* As_w = &As[wv * 1024];
  unsigned short* Bs_w = &Bs[wv * 1024];
  int rbase = (wv >> 1) * 64, cbase = (wv & 1) * 64;
  int fr = lane & 15, fk = (lane >> 4) * 8;

  for (int k0 = 0; k0 < H_DIM; k0 += BK) {
    gll16(aS0 + k0, As_w);
    gll16(aS1 + k0, As_w + 512);
    gll16(bS0 + k0, Bs_w);
    gll16(bS1 + k0, Bs_w + 512);
    __syncthreads();
    bf16x8 a[4], b[4];
#pragma unroll
    for (int m = 0; m < 4; m++)
      a[m] = *(const bf16x8*)&As[(rbase + m * 16 + fr) * BK + fk];
#pragma unroll
    for (int n = 0; n < 4; n++)
      b[n] = *(const bf16x8*)&Bs[(cbase + n * 16 + fr) * BK + fk];
#pragma unroll
    for (int m = 0; m < 4; m++)
#pragma unroll
      for (int n = 0; n < 4; n++)
        acc[m][n] = __builtin_amdgcn_mfma_f32_16x16x32_bf16(a[m], b[n], acc[m][n], 0, 0, 0);
    __syncthreads();
  }
  int rj = (lane >> 4) * 4;
#pragma unroll
  for (int m = 0; m < 4; m++) {
#pragma unroll
    for (int j = 0; j < 4; j++) {
      int r = rbase + m * 16 + rj + j;
      if (r < rows) {
        size_t rowp = (size_t)(slot0 + r) * E_DIM + eo0 + cbase + fr;
#pragma unroll
        for (int n = 0; n < 4; n++) Obuf[rowp + n * 16] = acc[m][n][j];
      }
    }
  }
}

// ------- combine: out[t] = w0*O[slot0] + w1*O[slot1] -------
__global__ __launch_bounds__(256) void combine_kernel(
    const float* __restrict__ Obuf, const int2* __restrict__ tok_slot,
    const float2* __restrict__ tok_w, float* __restrict__ out) {
  int t = blockIdx.x;
  int c = threadIdx.x * 4;
  int2 s = tok_slot[t];
  float2 wgt = tok_w[t];
  float4 a = *(const float4*)(Obuf + (size_t)s.x * E_DIM + c);
  float4 b = *(const float4*)(Obuf + (size_t)s.y * E_DIM + c);
  float4 o;
  o.x = wgt.x * a.x + wgt.y * b.x;
  o.y = wgt.x * a.y + wgt.y * b.y;
  o.z = wgt.x * a.z + wgt.y * b.z;
  o.w = wgt.x * a.w + wgt.y * b.w;
  *(float4*)(out + (size_t)t * E_DIM + c) = o;
}

extern "C" void kernel_launch(void* const* d_in, const int* in_sizes, int n_in,
                              void* d_out, int out_size, void* d_ws, size_t ws_size,
                              hipStream_t stream) {
  (void)in_sizes; (void)n_in; (void)out_size; (void)ws_size;
  const float* x = (const float*)d_in[0];
  const float* gate = (const float*)d_in[1];
  const float* w0 = (const float*)d_in[2];
  const float* w1 = (const float*)d_in[3];
  const float* wo = (const float*)d_in[4];
  float* out = (float*)d_out;
  char* ws = (char*)d_ws;

  int* cnt = (int*)(ws + 0);                       // 32B (+pad to 256)
  int2* tok_e = (int2*)(ws + 256);
  int2* tok_pos = (int2*)(ws + 256 + 32768);
  float2* tok_w = (float2*)(ws + 256 + 2 * 32768);
  int2* tok_slot = (int2*)(ws + 256 + 3 * 32768);
  int* tlist = (int*)(ws + 256 + 4 * 32768);
  size_t o = 256 + 5 * 32768;
  unsigned short* xb = (unsigned short*)(ws + o);  o += (size_t)T_TOKENS * E_DIM * 2;
  unsigned short* w0t = (unsigned short*)(ws + o); o += (size_t)8 * H_DIM * E_DIM * 2;
  unsigned short* w1t = (unsigned short*)(ws + o); o += (size_t)8 * H_DIM * E_DIM * 2;
  unsigned short* wot = (unsigned short*)(ws + o); o += (size_t)8 * E_DIM * H_DIM * 2;
  unsigned short* Mbuf = (unsigned short*)(ws + o); o += (size_t)8192 * H_DIM * 2;
  // O (32MB) aliases w0t/w1t (64MB) — dead after gemm1. Total ws ~136MB.
  float* Obuf = (float*)w0t;

  hipMemsetAsync(cnt, 0, 32, stream);
  hipLaunchKernelGGL(router_kernel, dim3(1024), dim3(256), 0, stream,
                     x, gate, cnt, tok_e, tok_pos, tok_w);
  hipLaunchKernelGGL(scatter_kernel, dim3(16), dim3(256), 0, stream,
                     cnt, tok_e, tok_pos, tlist, tok_slot);
  hipLaunchKernelGGL(convert_x_kernel, dim3(2048), dim3(256), 0, stream, x, xb);
  hipLaunchKernelGGL(transpose_convert_kernel, dim3(32, 16, 8), dim3(256), 0, stream,
                     w0, w0t, E_DIM, H_DIM);
  hipLaunchKernelGGL(transpose_convert_kernel, dim3(32, 16, 8), dim3(256), 0, stream,
                     w1, w1t, E_DIM, H_DIM);
  hipLaunchKernelGGL(transpose_convert_kernel, dim3(16, 32, 8), dim3(256), 0, stream,
                     wo, wot, H_DIM, E_DIM);
  hipLaunchKernelGGL(gemm1_kernel, dim3(16, MAX_TILES), dim3(256), 0, stream,
                     xb, w0t, w1t, cnt, tlist, Mbuf);
  hipLaunchKernelGGL(gemm2_kernel, dim3(8, MAX_TILES), dim3(256), 0, stream,
                     Mbuf, wot, cnt, Obuf);
  hipLaunchKernelGGL(combine_kernel, dim3(4096), dim3(256), 0, stream,
                     Obuf, tok_slot, tok_w, out);
}

// Round 3
// 501.232 us; speedup vs baseline: 1.2295x; 1.2295x over previous
//
#include <hip/hip_runtime.h>
#include <stdint.h>

// MoE block: B=2, L=2048 (T=4096 tokens), E=1024, H=2048, N=8 experts, top-2.
// Top-2-only expert compute (exact vs reference: other weights are 0).
// bf16 MFMA path. R2 (resubmit, bench was GPU-timeout): 128x64 GEMM tiles ->
// acc footprint 64/32 AGPR so 3-4 waves/SIMD resident (R1 fused 128x128
// dual-acc = 292 regs -> 1 block/CU, 10% occupancy, latency-bound at 350 TF).

#define T_TOKENS 4096
#define E_DIM 1024
#define H_DIM 2048
#define BM 128
#define BN 64
#define BK 32
#define MAX_TILES 72  // sum_e ceil(cnt_e/128) <= 8192/128 + 8

typedef __attribute__((ext_vector_type(8))) short bf16x8;
typedef __attribute__((ext_vector_type(8))) unsigned short u16x8;
typedef __attribute__((ext_vector_type(4))) float f32x4;

__device__ __forceinline__ unsigned short f2bf(float f) {
  unsigned u = __float_as_uint(f);
  u += 0x7fff + ((u >> 16) & 1);  // RNE
  return (unsigned short)(u >> 16);
}

__device__ __forceinline__ void gll16(const void* g, void* l) {
  // global -> LDS async, 16B per lane. LDS dest: wave-uniform base + lane*16.
  __builtin_amdgcn_global_load_lds(
      (__attribute__((address_space(1))) void*)(uintptr_t)g,
      (__attribute__((address_space(3))) void*)l, 16, 0, 0);
}

// -------- router: logits = x . gate, top2 + softmax; also emits xb (bf16) ----
__global__ __launch_bounds__(256) void router_kernel(
    const float* __restrict__ x, const float* __restrict__ gate,
    int* __restrict__ cnt, int2* __restrict__ tok_e,
    int2* __restrict__ tok_pos, float2* __restrict__ tok_w,
    unsigned short* __restrict__ xb) {
  int lane = threadIdx.x & 63;
  int wv = threadIdx.x >> 6;
  int t = blockIdx.x * 4 + wv;
  const float* xr = x + (size_t)t * E_DIM;
  unsigned short* xbr = xb + (size_t)t * E_DIM;
  float acc[8];
#pragma unroll
  for (int n = 0; n < 8; n++) acc[n] = 0.f;
#pragma unroll
  for (int i = 0; i < 16; i++) {
    int k = i * 64 + lane;
    float xv = xr[k];
    xbr[k] = f2bf(xv);  // fused x -> bf16 conversion
    const float4* gp = (const float4*)(gate + (size_t)k * 8);
    float4 g0 = gp[0], g1 = gp[1];
    acc[0] += xv * g0.x; acc[1] += xv * g0.y;
    acc[2] += xv * g0.z; acc[3] += xv * g0.w;
    acc[4] += xv * g1.x; acc[5] += xv * g1.y;
    acc[6] += xv * g1.z; acc[7] += xv * g1.w;
  }
#pragma unroll
  for (int s = 32; s >= 1; s >>= 1) {
#pragma unroll
    for (int n = 0; n < 8; n++) acc[n] += __shfl_xor(acc[n], s, 64);
  }
  if (lane == 0) {
    int i0 = 0; float v0 = acc[0];
#pragma unroll
    for (int n = 1; n < 8; n++) if (acc[n] > v0) { v0 = acc[n]; i0 = n; }
    int i1 = -1; float v1 = -3.4e38f;
#pragma unroll
    for (int n = 0; n < 8; n++) if (n != i0 && acc[n] > v1) { v1 = acc[n]; i1 = n; }
    float e1 = __expf(v1 - v0);
    float inv = 1.f / (1.f + e1);
    int p0 = atomicAdd(&cnt[i0], 1);
    int p1 = atomicAdd(&cnt[i1], 1);
    tok_e[t] = make_int2(i0, i1);
    tok_pos[t] = make_int2(p0, p1);
    tok_w[t] = make_float2(inv, e1 * inv);
  }
}

__global__ __launch_bounds__(256) void scatter_kernel(
    const int* __restrict__ cnt, const int2* __restrict__ tok_e,
    const int2* __restrict__ tok_pos, int* __restrict__ tlist,
    int2* __restrict__ tok_slot) {
  int t = blockIdx.x * 256 + threadIdx.x;
  if (t >= T_TOKENS) return;
  int offs[8]; int a = 0;
#pragma unroll
  for (int e = 0; e < 8; e++) { offs[e] = a; a += cnt[e]; }
  int2 te = tok_e[t]; int2 tp = tok_pos[t];
  int s0 = offs[te.x] + tp.x, s1 = offs[te.y] + tp.y;
  tlist[s0] = t; tlist[s1] = t;
  tok_slot[t] = make_int2(s0, s1);
}

// src fp32 [R][C] per batch z -> dst bf16 [C][R] (K-contiguous for MFMA B frags)
__global__ __launch_bounds__(256) void transpose_convert_kernel(
    const float* __restrict__ src, unsigned short* __restrict__ dst, int R, int C) {
  __shared__ float tile[64][65];
  size_t bofs = (size_t)blockIdx.z * R * C;
  const float* s = src + bofs;
  unsigned short* d = dst + bofs;
  int r0 = blockIdx.y * 64, c0 = blockIdx.x * 64;
  int tr = threadIdx.x >> 2;
  int tc = (threadIdx.x & 3) * 16;
  const float* sp = s + (size_t)(r0 + tr) * C + c0 + tc;
#pragma unroll
  for (int j = 0; j < 4; j++) {
    float4 v = ((const float4*)sp)[j];
    tile[tr][tc + j * 4 + 0] = v.x; tile[tr][tc + j * 4 + 1] = v.y;
    tile[tr][tc + j * 4 + 2] = v.z; tile[tr][tc + j * 4 + 3] = v.w;
  }
  __syncthreads();
  int co = tr;   // dst row (original col)
  int rc = tc;   // chunk of 16 original rows
  u16x8 o0, o1;
#pragma unroll
  for (int j = 0; j < 8; j++) o0[j] = f2bf(tile[rc + j][co]);
#pragma unroll
  for (int j = 0; j < 8; j++) o1[j] = f2bf(tile[rc + 8 + j][co]);
  unsigned short* dp = d + (size_t)(c0 + co) * R + r0 + rc;
  *(u16x8*)dp = o0;
  *(u16x8*)(dp + 8) = o1;
}

// ---------------- tile mapping helper (per-expert row tiles) ----------------
__device__ __forceinline__ bool map_tile(const int* cnt, int tile, int& eSel,
                                         int& slot0, int& rows) {
  eSel = -1;
  int acc = 0, off = 0;
  for (int e = 0; e < 8; e++) {
    int ce = cnt[e];
    int te = (ce + BM - 1) / BM;
    if (eSel < 0 && tile < acc + te) {
      eSel = e;
      int tin = tile - acc;
      slot0 = off + tin * BM;
      rows = min(BM, ce - tin * BM);
    }
    acc += te; off += ce;
  }
  return eSel >= 0;
}

// ------- GEMM1: gathered X[slot] @ {w0t,w1t} -> M = silu(h0)*h1 (bf16) -------
// Block tile 128x64, 4 waves each own 64x32 of both h0 and h1.
__global__ __launch_bounds__(256, 3) void gemm1_kernel(
    const unsigned short* __restrict__ xb,    // [4096][1024] bf16
    const unsigned short* __restrict__ w0t,   // [8][2048][1024] bf16 (h-major)
    const unsigned short* __restrict__ w1t,
    const int* __restrict__ cnt, const int* __restrict__ tlist,
    unsigned short* __restrict__ Mbuf) {      // [8192][2048] bf16
  __shared__ alignas(16) unsigned short As[BM * BK];   // 8KB
  __shared__ alignas(16) unsigned short B0s[BN * BK];  // 4KB
  __shared__ alignas(16) unsigned short B1s[BN * BK];  // 4KB

  int eSel, slot0, rows;
  if (!map_tile(cnt, blockIdx.y, eSel, slot0, rows)) return;
  int h0 = blockIdx.x * BN;

  int tid = threadIdx.x, lane = tid & 63, wv = tid >> 6;
  int sr = lane >> 2;             // 0..15 staging row within chunk
  int colE = (lane & 3) * 8;      // staging col (elements)
  int ar0 = wv * 32 + sr, ar1 = ar0 + 16;         // A rows for this wave
  int ra0 = min(ar0, rows - 1), ra1 = min(ar1, rows - 1);
  const unsigned short* aS0 = xb + (size_t)tlist[slot0 + ra0] * E_DIM + colE;
  const unsigned short* aS1 = xb + (size_t)tlist[slot0 + ra1] * E_DIM + colE;
  int br = wv * 16 + sr;                          // B row (h) for this wave
  const unsigned short* b0S = w0t + ((size_t)eSel * H_DIM + h0 + br) * E_DIM + colE;
  const unsigned short* b1S = w1t + ((size_t)eSel * H_DIM + h0 + br) * E_DIM + colE;

  f32x4 acc0[4][2], acc1[4][2];
  f32x4 fz = {0.f, 0.f, 0.f, 0.f};
#pragma unroll
  for (int m = 0; m < 4; m++)
#pragma unroll
    for (int n = 0; n < 2; n++) { acc0[m][n] = fz; acc1[m][n] = fz; }

  unsigned short* As_w = &As[wv * 1024];   // 32 rows x 32
  unsigned short* B0s_w = &B0s[wv * 512];  // 16 rows x 32
  unsigned short* B1s_w = &B1s[wv * 512];
  int rbase = (wv >> 1) * 64, cbase = (wv & 1) * 32;
  int fr = lane & 15, fk = (lane >> 4) * 8;

  for (int k0 = 0; k0 < E_DIM; k0 += BK) {
    gll16(aS0 + k0, As_w);
    gll16(aS1 + k0, As_w + 512);
    gll16(b0S + k0, B0s_w);
    gll16(b1S + k0, B1s_w);
    __syncthreads();
    bf16x8 a[4], b0[2], b1[2];
#pragma unroll
    for (int m = 0; m < 4; m++)
      a[m] = *(const bf16x8*)&As[(rbase + m * 16 + fr) * BK + fk];
#pragma unroll
    for (int n = 0; n < 2; n++) {
      b0[n] = *(const bf16x8*)&B0s[(cbase + n * 16 + fr) * BK + fk];
      b1[n] = *(const bf16x8*)&B1s[(cbase + n * 16 + fr) * BK + fk];
    }
#pragma unroll
    for (int m = 0; m < 4; m++)
#pragma unroll
      for (int n = 0; n < 2; n++) {
        acc0[m][n] = __builtin_amdgcn_mfma_f32_16x16x32_bf16(a[m], b0[n], acc0[m][n], 0, 0, 0);
        acc1[m][n] = __builtin_amdgcn_mfma_f32_16x16x32_bf16(a[m], b1[n], acc1[m][n], 0, 0, 0);
      }
    __syncthreads();
  }
  int rj = (lane >> 4) * 4;
#pragma unroll
  for (int m = 0; m < 4; m++) {
#pragma unroll
    for (int j = 0; j < 4; j++) {
      int r = rbase + m * 16 + rj + j;
      if (r < rows) {
        size_t rowp = (size_t)(slot0 + r) * H_DIM + h0 + cbase + fr;
#pragma unroll
        for (int n = 0; n < 2; n++) {
          float v0 = acc0[m][n][j], v1 = acc1[m][n][j];
          float mv = v0 / (1.f + __expf(-v0)) * v1;  // silu(h0)*h1
          Mbuf[rowp + n * 16] = f2bf(mv);
        }
      }
    }
  }
}

// ------- GEMM2: M[slot] @ wot -> O (fp32) -------
__global__ __launch_bounds__(256, 4) void gemm2_kernel(
    const unsigned short* __restrict__ Mbuf,  // [8192][2048] bf16
    const unsigned short* __restrict__ wot,   // [8][1024][2048] bf16 (eo-major)
    const int* __restrict__ cnt,
    float* __restrict__ Obuf) {               // [8192][1024] fp32
  __shared__ alignas(16) unsigned short As[BM * BK];  // 8KB
  __shared__ alignas(16) unsigned short Bs[BN * BK];  // 4KB

  int eSel, slot0, rows;
  if (!map_tile(cnt, blockIdx.y, eSel, slot0, rows)) return;
  int eo0 = blockIdx.x * BN;

  int tid = threadIdx.x, lane = tid & 63, wv = tid >> 6;
  int sr = lane >> 2;
  int colE = (lane & 3) * 8;
  int ar0 = wv * 32 + sr, ar1 = ar0 + 16;
  int ra0 = min(ar0, rows - 1), ra1 = min(ar1, rows - 1);
  const unsigned short* aS0 = Mbuf + (size_t)(slot0 + ra0) * H_DIM + colE;
  const unsigned short* aS1 = Mbuf + (size_t)(slot0 + ra1) * H_DIM + colE;
  int br = wv * 16 + sr;
  const unsigned short* bS = wot + ((size_t)eSel * E_DIM + eo0 + br) * H_DIM + colE;

  f32x4 acc[4][2];
  f32x4 fz = {0.f, 0.f, 0.f, 0.f};
#pragma unroll
  for (int m = 0; m < 4; m++)
#pragma unroll
    for (int n = 0; n < 2; n++) acc[m][n] = fz;

  unsigned short* As_w = &As[wv * 1024];
  unsigned short* Bs_w = &Bs[wv * 512];
  int rbase = (wv >> 1) * 64, cbase = (wv & 1) * 32;
  int fr = lane & 15, fk = (lane >> 4) * 8;

  for (int k0 = 0; k0 < H_DIM; k0 += BK) {
    gll16(aS0 + k0, As_w);
    gll16(aS1 + k0, As_w + 512);
    gll16(bS + k0, Bs_w);
    __syncthreads();
    bf16x8 a[4], b[2];
#pragma unroll
    for (int m = 0; m < 4; m++)
      a[m] = *(const bf16x8*)&As[(rbase + m * 16 + fr) * BK + fk];
#pragma unroll
    for (int n = 0; n < 2; n++)
      b[n] = *(const bf16x8*)&Bs[(cbase + n * 16 + fr) * BK + fk];
#pragma unroll
    for (int m = 0; m < 4; m++)
#pragma unroll
      for (int n = 0; n < 2; n++)
        acc[m][n] = __builtin_amdgcn_mfma_f32_16x16x32_bf16(a[m], b[n], acc[m][n], 0, 0, 0);
    __syncthreads();
  }
  int rj = (lane >> 4) * 4;
#pragma unroll
  for (int m = 0; m < 4; m++) {
#pragma unroll
    for (int j = 0; j < 4; j++) {
      int r = rbase + m * 16 + rj + j;
      if (r < rows) {
        size_t rowp = (size_t)(slot0 + r) * E_DIM + eo0 + cbase + fr;
#pragma unroll
        for (int n = 0; n < 2; n++) Obuf[rowp + n * 16] = acc[m][n][j];
      }
    }
  }
}

// ------- combine: out[t] = w0*O[slot0] + w1*O[slot1] -------
__global__ __launch_bounds__(256) void combine_kernel(
    const float* __restrict__ Obuf, const int2* __restrict__ tok_slot,
    const float2* __restrict__ tok_w, float* __restrict__ out) {
  int t = blockIdx.x;
  int c = threadIdx.x * 4;
  int2 s = tok_slot[t];
  float2 wgt = tok_w[t];
  float4 a = *(const float4*)(Obuf + (size_t)s.x * E_DIM + c);
  float4 b = *(const float4*)(Obuf + (size_t)s.y * E_DIM + c);
  float4 o;
  o.x = wgt.x * a.x + wgt.y * b.x;
  o.y = wgt.x * a.y + wgt.y * b.y;
  o.z = wgt.x * a.z + wgt.y * b.z;
  o.w = wgt.x * a.w + wgt.y * b.w;
  *(float4*)(out + (size_t)t * E_DIM + c) = o;
}

extern "C" void kernel_launch(void* const* d_in, const int* in_sizes, int n_in,
                              void* d_out, int out_size, void* d_ws, size_t ws_size,
                              hipStream_t stream) {
  (void)in_sizes; (void)n_in; (void)out_size; (void)ws_size;
  const float* x = (const float*)d_in[0];
  const float* gate = (const float*)d_in[1];
  const float* w0 = (const float*)d_in[2];
  const float* w1 = (const float*)d_in[3];
  const float* wo = (const float*)d_in[4];
  float* out = (float*)d_out;
  char* ws = (char*)d_ws;

  int* cnt = (int*)(ws + 0);                       // 32B (+pad to 256)
  int2* tok_e = (int2*)(ws + 256);
  int2* tok_pos = (int2*)(ws + 256 + 32768);
  float2* tok_w = (float2*)(ws + 256 + 2 * 32768);
  int2* tok_slot = (int2*)(ws + 256 + 3 * 32768);
  int* tlist = (int*)(ws + 256 + 4 * 32768);
  size_t o = 256 + 5 * 32768;
  unsigned short* xb = (unsigned short*)(ws + o);  o += (size_t)T_TOKENS * E_DIM * 2;
  unsigned short* w0t = (unsigned short*)(ws + o); o += (size_t)8 * H_DIM * E_DIM * 2;
  unsigned short* w1t = (unsigned short*)(ws + o); o += (size_t)8 * H_DIM * E_DIM * 2;
  unsigned short* wot = (unsigned short*)(ws + o); o += (size_t)8 * E_DIM * H_DIM * 2;
  unsigned short* Mbuf = (unsigned short*)(ws + o); o += (size_t)8192 * H_DIM * 2;
  // O (32MB) aliases w0t/w1t (64MB) — dead after gemm1. Total ws ~136MB.
  float* Obuf = (float*)w0t;

  hipMemsetAsync(cnt, 0, 32, stream);
  hipLaunchKernelGGL(router_kernel, dim3(1024), dim3(256), 0, stream,
                     x, gate, cnt, tok_e, tok_pos, tok_w, xb);
  hipLaunchKernelGGL(scatter_kernel, dim3(16), dim3(256), 0, stream,
                     cnt, tok_e, tok_pos, tlist, tok_slot);
  hipLaunchKernelGGL(transpose_convert_kernel, dim3(32, 16, 8), dim3(256), 0, stream,
                     w0, w0t, E_DIM, H_DIM);
  hipLaunchKernelGGL(transpose_convert_kernel, dim3(32, 16, 8), dim3(256), 0, stream,
                     w1, w1t, E_DIM, H_DIM);
  hipLaunchKernelGGL(transpose_convert_kernel, dim3(16, 32, 8), dim3(256), 0, stream,
                     wo, wot, H_DIM, E_DIM);
  hipLaunchKernelGGL(gemm1_kernel, dim3(32, MAX_TILES), dim3(256), 0, stream,
                     xb, w0t, w1t, cnt, tlist, Mbuf);
  hipLaunchKernelGGL(gemm2_kernel, dim3(16, MAX_TILES), dim3(256), 0, stream,
                     Mbuf, wot, cnt, Obuf);
  hipLaunchKernelGGL(combine_kernel, dim3(4096), dim3(256), 0, stream,
                     Obuf, tok_slot, tok_w, out);
}

// Round 4
// 490.038 us; speedup vs baseline: 1.2575x; 1.0228x over previous
//
#include <hip/hip_runtime.h>
#include <stdint.h>

// MoE block: B=2, L=2048 (T=4096 tokens), E=1024, H=2048, N=8 experts, top-2.
// Top-2-only expert compute (exact vs reference: other weights are 0).
// R4: BK=64 + both-sides XOR bank-swizzle (T2, rule#21: linear LDS dest via
// global_load_lds, pre-swizzled per-lane GLOBAL source, swizzled ds_read).
// gemm2 -> 128x128 m97 geometry + fused combine via fp32 atomicAdd.
// R3 evidence: occupancy fix landed (10->36%, 196->109us); 8.8M bank-conflict
// cycles now on critical path ([row][32]bf16 = 8-way on ds_read_b128).

#define T_TOKENS 4096
#define E_DIM 1024
#define H_DIM 2048
#define BM 128
#define BK 64   // 128B LDS rows: 8 x 16B slots -> XOR swizzle spans all 8 bank-quads
#define MAX_TILES 72  // sum_e ceil(cnt_e/128) <= 8192/128 + 8

typedef __attribute__((ext_vector_type(8))) short bf16x8;
typedef __attribute__((ext_vector_type(8))) unsigned short u16x8;
typedef __attribute__((ext_vector_type(4))) float f32x4;

__device__ __forceinline__ unsigned short f2bf(float f) {
  unsigned u = __float_as_uint(f);
  u += 0x7fff + ((u >> 16) & 1);  // RNE
  return (unsigned short)(u >> 16);
}

__device__ __forceinline__ void gll16(const void* g, void* l) {
  // global -> LDS async, 16B/lane. LDS dest: wave-uniform base + lane*16 (linear).
  __builtin_amdgcn_global_load_lds(
      (__attribute__((address_space(1))) void*)(uintptr_t)g,
      (__attribute__((address_space(3))) void*)l, 16, 0, 0);
}

// Swizzle invariant (both sides): LDS(row, s_phys) holds global(row, s_phys ^ (row&7)).
// Stage: lane l of 8-row group j has row%8 = l>>3, s_phys = l&7 -> global slot (l&7)^(l>>3).
// Read: logical slot g of row -> s_phys = g ^ (row&7); row&7 == fr&7 for all our bases.

// -------- router: logits = x . gate, top2 + softmax; also emits xb (bf16) ----
__global__ __launch_bounds__(256) void router_kernel(
    const float* __restrict__ x, const float* __restrict__ gate,
    int* __restrict__ cnt, int2* __restrict__ tok_e,
    int2* __restrict__ tok_pos, float2* __restrict__ tok_w,
    unsigned short* __restrict__ xb) {
  int lane = threadIdx.x & 63;
  int wv = threadIdx.x >> 6;
  int t = blockIdx.x * 4 + wv;
  const float* xr = x + (size_t)t * E_DIM;
  unsigned short* xbr = xb + (size_t)t * E_DIM;
  float acc[8];
#pragma unroll
  for (int n = 0; n < 8; n++) acc[n] = 0.f;
#pragma unroll
  for (int i = 0; i < 4; i++) {
    int k4 = i * 256 + lane * 4;
    float4 xv = *(const float4*)(xr + k4);
    ushort4 ov;
    ov.x = f2bf(xv.x); ov.y = f2bf(xv.y); ov.z = f2bf(xv.z); ov.w = f2bf(xv.w);
    *(ushort4*)(xbr + k4) = ov;
    float xa[4] = {xv.x, xv.y, xv.z, xv.w};
#pragma unroll
    for (int c = 0; c < 4; c++) {
      const float4* gp = (const float4*)(gate + (size_t)(k4 + c) * 8);
      float4 g0 = gp[0], g1 = gp[1];
      acc[0] += xa[c] * g0.x; acc[1] += xa[c] * g0.y;
      acc[2] += xa[c] * g0.z; acc[3] += xa[c] * g0.w;
      acc[4] += xa[c] * g1.x; acc[5] += xa[c] * g1.y;
      acc[6] += xa[c] * g1.z; acc[7] += xa[c] * g1.w;
    }
  }
#pragma unroll
  for (int s = 32; s >= 1; s >>= 1) {
#pragma unroll
    for (int n = 0; n < 8; n++) acc[n] += __shfl_xor(acc[n], s, 64);
  }
  if (lane == 0) {
    int i0 = 0; float v0 = acc[0];
#pragma unroll
    for (int n = 1; n < 8; n++) if (acc[n] > v0) { v0 = acc[n]; i0 = n; }
    int i1 = -1; float v1 = -3.4e38f;
#pragma unroll
    for (int n = 0; n < 8; n++) if (n != i0 && acc[n] > v1) { v1 = acc[n]; i1 = n; }
    float e1 = __expf(v1 - v0);
    float inv = 1.f / (1.f + e1);
    int p0 = atomicAdd(&cnt[i0], 1);
    int p1 = atomicAdd(&cnt[i1], 1);
    tok_e[t] = make_int2(i0, i1);
    tok_pos[t] = make_int2(p0, p1);
    tok_w[t] = make_float2(inv, e1 * inv);
  }
}

__global__ __launch_bounds__(256) void scatter_kernel(
    const int* __restrict__ cnt, const int2* __restrict__ tok_e,
    const int2* __restrict__ tok_pos, const float2* __restrict__ tok_w,
    int* __restrict__ tlist, float* __restrict__ wlist) {
  int t = blockIdx.x * 256 + threadIdx.x;
  if (t >= T_TOKENS) return;
  int offs[8]; int a = 0;
#pragma unroll
  for (int e = 0; e < 8; e++) { offs[e] = a; a += cnt[e]; }
  int2 te = tok_e[t]; int2 tp = tok_pos[t];
  float2 w = tok_w[t];
  int s0 = offs[te.x] + tp.x, s1 = offs[te.y] + tp.y;
  tlist[s0] = t; tlist[s1] = t;
  wlist[s0] = w.x; wlist[s1] = w.y;
}

// src fp32 [R][C] per batch z -> dst bf16 [C][R] (K-contiguous for MFMA frags)
__global__ __launch_bounds__(256) void transpose_convert_kernel(
    const float* __restrict__ src, unsigned short* __restrict__ dst, int R, int C) {
  __shared__ float tile[64][65];
  size_t bofs = (size_t)blockIdx.z * R * C;
  const float* s = src + bofs;
  unsigned short* d = dst + bofs;
  int r0 = blockIdx.y * 64, c0 = blockIdx.x * 64;
  int tr = threadIdx.x >> 2;
  int tc = (threadIdx.x & 3) * 16;
  const float* sp = s + (size_t)(r0 + tr) * C + c0 + tc;
#pragma unroll
  for (int j = 0; j < 4; j++) {
    float4 v = ((const float4*)sp)[j];
    tile[tr][tc + j * 4 + 0] = v.x; tile[tr][tc + j * 4 + 1] = v.y;
    tile[tr][tc + j * 4 + 2] = v.z; tile[tr][tc + j * 4 + 3] = v.w;
  }
  __syncthreads();
  int co = tr;   // dst row (original col)
  int rc = tc;   // chunk of 16 original rows
  u16x8 o0, o1;
#pragma unroll
  for (int j = 0; j < 8; j++) o0[j] = f2bf(tile[rc + j][co]);
#pragma unroll
  for (int j = 0; j < 8; j++) o1[j] = f2bf(tile[rc + 8 + j][co]);
  unsigned short* dp = d + (size_t)(c0 + co) * R + r0 + rc;
  *(u16x8*)dp = o0;
  *(u16x8*)(dp + 8) = o1;
}

// ---------------- tile mapping helper (per-expert row tiles) ----------------
__device__ __forceinline__ bool map_tile(const int* cnt, int tile, int& eSel,
                                         int& slot0, int& rows) {
  eSel = -1;
  int acc = 0, off = 0;
  for (int e = 0; e < 8; e++) {
    int ce = cnt[e];
    int te = (ce + BM - 1) / BM;
    if (eSel < 0 && tile < acc + te) {
      eSel = e;
      int tin = tile - acc;
      slot0 = off + tin * BM;
      rows = min(BM, ce - tin * BM);
    }
    acc += te; off += ce;
  }
  return eSel >= 0;
}

// ------- GEMM1: gathered X[slot] @ {w0t,w1t} -> M = silu(h0)*h1 (bf16) -------
// 128x64 tile, 4 waves own 64x32 of both h0,h1. BK=64 swizzled LDS.
__global__ __launch_bounds__(256, 3) void gemm1_kernel(
    const unsigned short* __restrict__ xb,    // [4096][1024] bf16
    const unsigned short* __restrict__ w0t,   // [8][2048][1024] bf16 (h-major)
    const unsigned short* __restrict__ w1t,
    const int* __restrict__ cnt, const int* __restrict__ tlist,
    unsigned short* __restrict__ Mbuf) {      // [8192][2048] bf16
  __shared__ alignas(16) unsigned short As[BM * BK];   // 16KB
  __shared__ alignas(16) unsigned short B0s[64 * BK];  // 8KB
  __shared__ alignas(16) unsigned short B1s[64 * BK];  // 8KB

  int eSel, slot0, rows;
  if (!map_tile(cnt, blockIdx.y, eSel, slot0, rows)) return;
  int h0 = blockIdx.x * 64;

  int tid = threadIdx.x, lane = tid & 63, wv = tid >> 6;
  int lr = lane >> 3;               // row within 8-row staging group
  int swz = ((lane & 7) ^ lr) * 8;  // pre-swizzled global elem offset

  const unsigned short* aP[4];
#pragma unroll
  for (int j = 0; j < 4; j++) {
    int r = wv * 32 + j * 8 + lr;
    int rc = min(r, rows - 1);
    aP[j] = xb + (size_t)tlist[slot0 + rc] * E_DIM + swz;
  }
  const unsigned short* b0P[2];
  const unsigned short* b1P[2];
#pragma unroll
  for (int j = 0; j < 2; j++) {
    int hr = h0 + wv * 16 + j * 8 + lr;
    b0P[j] = w0t + ((size_t)eSel * H_DIM + hr) * E_DIM + swz;
    b1P[j] = w1t + ((size_t)eSel * H_DIM + hr) * E_DIM + swz;
  }

  f32x4 acc0[4][2], acc1[4][2];
  f32x4 fz = {0.f, 0.f, 0.f, 0.f};
#pragma unroll
  for (int m = 0; m < 4; m++)
#pragma unroll
    for (int n = 0; n < 2; n++) { acc0[m][n] = fz; acc1[m][n] = fz; }

  unsigned short* AsW = &As[wv * 2048];   // 32 rows x 64
  unsigned short* B0W = &B0s[wv * 1024];  // 16 rows x 64
  unsigned short* B1W = &B1s[wv * 1024];
  int rbase = (wv >> 1) * 64, cbase = (wv & 1) * 32;
  int fr = lane & 15, q = lane >> 4, fx = fr & 7;

  for (int k0 = 0; k0 < E_DIM; k0 += BK) {
#pragma unroll
    for (int j = 0; j < 4; j++) gll16(aP[j] + k0, AsW + j * 512);
#pragma unroll
    for (int j = 0; j < 2; j++) {
      gll16(b0P[j] + k0, B0W + j * 512);
      gll16(b1P[j] + k0, B1W + j * 512);
    }
    __syncthreads();
#pragma unroll
    for (int kk = 0; kk < 2; kk++) {
      int so = ((kk * 4 + q) ^ fx) * 8;  // swizzled 16B slot
      bf16x8 a[4], b0[2], b1[2];
#pragma unroll
      for (int m = 0; m < 4; m++)
        a[m] = *(const bf16x8*)&As[(rbase + m * 16 + fr) * BK + so];
#pragma unroll
      for (int n = 0; n < 2; n++) {
        b0[n] = *(const bf16x8*)&B0s[(cbase + n * 16 + fr) * BK + so];
        b1[n] = *(const bf16x8*)&B1s[(cbase + n * 16 + fr) * BK + so];
      }
#pragma unroll
      for (int m = 0; m < 4; m++)
#pragma unroll
        for (int n = 0; n < 2; n++) {
          acc0[m][n] = __builtin_amdgcn_mfma_f32_16x16x32_bf16(a[m], b0[n], acc0[m][n], 0, 0, 0);
          acc1[m][n] = __builtin_amdgcn_mfma_f32_16x16x32_bf16(a[m], b1[n], acc1[m][n], 0, 0, 0);
        }
    }
    __syncthreads();
  }
  int rj = q * 4;
#pragma unroll
  for (int m = 0; m < 4; m++) {
#pragma unroll
    for (int j = 0; j < 4; j++) {
      int r = rbase + m * 16 + rj + j;
      if (r < rows) {
        size_t rowp = (size_t)(slot0 + r) * H_DIM + h0 + cbase + fr;
#pragma unroll
        for (int n = 0; n < 2; n++) {
          float v0 = acc0[m][n][j], v1 = acc1[m][n][j];
          float mv = v0 / (1.f + __expf(-v0)) * v1;  // silu(h0)*h1
          Mbuf[rowp + n * 16] = f2bf(mv);
        }
      }
    }
  }
}

// ------- GEMM2: M[slot] @ wot -> out, fused combine via atomicAdd -------
// 128x128 m97 geometry, BK=64 swizzled. Each out element gets exactly 2 adds.
__global__ __launch_bounds__(256, 3) void gemm2_kernel(
    const unsigned short* __restrict__ Mbuf,  // [8192][2048] bf16
    const unsigned short* __restrict__ wot,   // [8][1024][2048] bf16 (eo-major)
    const int* __restrict__ cnt, const int* __restrict__ tlist,
    const float* __restrict__ wlist,
    float* __restrict__ out) {                // [4096][1024] fp32 (zero-init)
  __shared__ alignas(16) unsigned short As[BM * BK];  // 16KB
  __shared__ alignas(16) unsigned short Bs[BM * BK];  // 16KB

  int eSel, slot0, rows;
  if (!map_tile(cnt, blockIdx.y, eSel, slot0, rows)) return;
  int eo0 = blockIdx.x * 128;

  int tid = threadIdx.x, lane = tid & 63, wv = tid >> 6;
  int lr = lane >> 3;
  int swz = ((lane & 7) ^ lr) * 8;

  const unsigned short* aP[4];
  const unsigned short* bP[4];
#pragma unroll
  for (int j = 0; j < 4; j++) {
    int r = wv * 32 + j * 8 + lr;
    int rc = min(r, rows - 1);
    aP[j] = Mbuf + (size_t)(slot0 + rc) * H_DIM + swz;
    bP[j] = wot + ((size_t)eSel * E_DIM + eo0 + r) * H_DIM + swz;
  }

  f32x4 acc[4][4];
  f32x4 fz = {0.f, 0.f, 0.f, 0.f};
#pragma unroll
  for (int m = 0; m < 4; m++)
#pragma unroll
    for (int n = 0; n < 4; n++) acc[m][n] = fz;

  unsigned short* AsW = &As[wv * 2048];
  unsigned short* BsW = &Bs[wv * 2048];
  int rbase = (wv >> 1) * 64, cbase = (wv & 1) * 64;
  int fr = lane & 15, q = lane >> 4, fx = fr & 7;

  for (int k0 = 0; k0 < H_DIM; k0 += BK) {
#pragma unroll
    for (int j = 0; j < 4; j++) {
      gll16(aP[j] + k0, AsW + j * 512);
      gll16(bP[j] + k0, BsW + j * 512);
    }
    __syncthreads();
#pragma unroll
    for (int kk = 0; kk < 2; kk++) {
      int so = ((kk * 4 + q) ^ fx) * 8;
      bf16x8 a[4], b[4];
#pragma unroll
      for (int m = 0; m < 4; m++)
        a[m] = *(const bf16x8*)&As[(rbase + m * 16 + fr) * BK + so];
#pragma unroll
      for (int n = 0; n < 4; n++)
        b[n] = *(const bf16x8*)&Bs[(cbase + n * 16 + fr) * BK + so];
#pragma unroll
      for (int m = 0; m < 4; m++)
#pragma unroll
        for (int n = 0; n < 4; n++)
          acc[m][n] = __builtin_amdgcn_mfma_f32_16x16x32_bf16(a[m], b[n], acc[m][n], 0, 0, 0);
    }
    __syncthreads();
  }
  int rj = q * 4;
#pragma unroll
  for (int m = 0; m < 4; m++) {
#pragma unroll
    for (int j = 0; j < 4; j++) {
      int r = rbase + m * 16 + rj + j;
      if (r < rows) {
        int s = slot0 + r;
        int tok = tlist[s];
        float w = wlist[s];
        float* orow = out + (size_t)tok * E_DIM + eo0 + cbase + fr;
#pragma unroll
        for (int n = 0; n < 4; n++)
          atomicAdd(orow + n * 16, w * acc[m][n][j]);
      }
    }
  }
}

extern "C" void kernel_launch(void* const* d_in, const int* in_sizes, int n_in,
                              void* d_out, int out_size, void* d_ws, size_t ws_size,
                              hipStream_t stream) {
  (void)in_sizes; (void)n_in; (void)out_size; (void)ws_size;
  const float* x = (const float*)d_in[0];
  const float* gate = (const float*)d_in[1];
  const float* w0 = (const float*)d_in[2];
  const float* w1 = (const float*)d_in[3];
  const float* wo = (const float*)d_in[4];
  float* out = (float*)d_out;
  char* ws = (char*)d_ws;

  int* cnt = (int*)(ws + 0);                       // 32B (+pad to 256)
  int2* tok_e = (int2*)(ws + 256);
  int2* tok_pos = (int2*)(ws + 256 + 32768);
  float2* tok_w = (float2*)(ws + 256 + 2 * 32768);
  int* tlist = (int*)(ws + 256 + 3 * 32768);
  float* wlist = (float*)(ws + 256 + 4 * 32768);
  size_t o = 256 + 5 * 32768;
  unsigned short* xb = (unsigned short*)(ws + o);  o += (size_t)T_TOKENS * E_DIM * 2;
  unsigned short* w0t = (unsigned short*)(ws + o); o += (size_t)8 * H_DIM * E_DIM * 2;
  unsigned short* w1t = (unsigned short*)(ws + o); o += (size_t)8 * H_DIM * E_DIM * 2;
  unsigned short* wot = (unsigned short*)(ws + o); o += (size_t)8 * E_DIM * H_DIM * 2;
  unsigned short* Mbuf = (unsigned short*)(ws + o); o += (size_t)8192 * H_DIM * 2;

  hipMemsetAsync(cnt, 0, 32, stream);
  hipMemsetAsync(out, 0, (size_t)T_TOKENS * E_DIM * 4, stream);  // atomic target
  hipLaunchKernelGGL(router_kernel, dim3(1024), dim3(256), 0, stream,
                     x, gate, cnt, tok_e, tok_pos, tok_w, xb);
  hipLaunchKernelGGL(scatter_kernel, dim3(16), dim3(256), 0, stream,
                     cnt, tok_e, tok_pos, tok_w, tlist, wlist);
  hipLaunchKernelGGL(transpose_convert_kernel, dim3(32, 16, 8), dim3(256), 0, stream,
                     w0, w0t, E_DIM, H_DIM);
  hipLaunchKernelGGL(transpose_convert_kernel, dim3(32, 16, 8), dim3(256), 0, stream,
                     w1, w1t, E_DIM, H_DIM);
  hipLaunchKernelGGL(transpose_convert_kernel, dim3(16, 32, 8), dim3(256), 0, stream,
                     wo, wot, H_DIM, E_DIM);
  hipLaunchKernelGGL(gemm1_kernel, dim3(32, MAX_TILES), dim3(256), 0, stream,
                     xb, w0t, w1t, cnt, tlist, Mbuf);
  hipLaunchKernelGGL(gemm2_kernel, dim3(8, MAX_TILES), dim3(256), 0, stream,
                     Mbuf, wot, cnt, tlist, wlist, out);
}